// Round 1
// 621.906 us; speedup vs baseline: 1.0719x; 1.0719x over previous
//
#include <hip/hip_runtime.h>
#include <math.h>

#define BATCH 16

typedef __attribute__((ext_vector_type(8))) short s16x8;
typedef __attribute__((ext_vector_type(8))) unsigned short u16x8;
typedef __attribute__((ext_vector_type(4))) float f32x4;

__device__ inline unsigned short f2bf_rn(float f) {
  unsigned u = __float_as_uint(f);
  u += 0x7FFF + ((u >> 16) & 1);
  return (unsigned short)(u >> 16);
}
__device__ inline float bf2f(unsigned short h) {
  return __uint_as_float(((unsigned)h) << 16);
}

// Async global->LDS DMA, 16B per lane. LDS dest is wave-uniform base + lane*16.
__device__ __forceinline__ void gload16(const unsigned short* g, unsigned short* l) {
  __builtin_amdgcn_global_load_lds(
      (__attribute__((address_space(1))) void*)g,
      (__attribute__((address_space(3))) void*)l, 16, 0, 0);
}

// ---------------------------------------------------------------------------
// Elementwise fp32 -> (bf16 hi, bf16 lo) split. 4 elems/thread.
// ---------------------------------------------------------------------------
__global__ __launch_bounds__(256) void cvt_split(
    const float* __restrict__ X, unsigned short* __restrict__ H,
    unsigned short* __restrict__ L) {
  const size_t i = (((size_t)blockIdx.x << 8) + threadIdx.x) << 2;
  f32x4 v = *(const f32x4*)(X + i);
  ushort4 h, l;
  h.x = f2bf_rn(v[0]); l.x = f2bf_rn(v[0] - bf2f(h.x));
  h.y = f2bf_rn(v[1]); l.y = f2bf_rn(v[1] - bf2f(h.y));
  h.z = f2bf_rn(v[2]); l.z = f2bf_rn(v[2] - bf2f(h.z));
  h.w = f2bf_rn(v[3]); l.w = f2bf_rn(v[3] - bf2f(h.w));
  *(ushort4*)(H + i) = h;
  *(ushort4*)(L + i) = l;
}

// ---------------------------------------------------------------------------
// Split-bf16 GEMM, hi/lo preconverted: C = A*B^T fp32-accurate.
// global_load_lds staging (m97 structure), linear LDS [128][32] with
// slot-XOR swizzle (slot ^= (row>>1)&3) applied on BOTH the per-lane global
// source address and the frag-read address -> 2-way (free) bank pattern.
// Grid: flat 1024 blocks, bijective XCD swizzle for L2 locality.
// ---------------------------------------------------------------------------
template <int SPLIT_OUT>
__global__ __launch_bounds__(256) void gemm_split3b(
    const unsigned short* __restrict__ AH, const unsigned short* __restrict__ AL,
    const unsigned short* __restrict__ BH, const unsigned short* __restrict__ BL,
    void* __restrict__ Cout, void* __restrict__ CoutL,
    long long sA, long long sB, long long sC) {
  __shared__ unsigned short Ahs[128 * 32], Als[128 * 32];
  __shared__ unsigned short Bhs[128 * 32], Bls[128 * 32];
  const int tid = threadIdx.x;
  // XCD swizzle: nwg==1024 (divisible by 8) -> contiguous 128-block chunk/XCD
  const int wg = ((blockIdx.x & 7) << 7) | (blockIdx.x >> 3);
  int bm, bn, z;
  if (SPLIT_OUT) {  // proj: M=16384 flat, N=1024
    z = 0; bm = (wg >> 3) << 7; bn = (wg & 7) << 7;
  } else {          // sim: batched 16 x (1024x1024); XCD owns 2 batches
    z = wg >> 6; bm = ((wg >> 3) & 7) << 7; bn = (wg & 7) << 7;
  }
  const size_t oA = (size_t)z * sA, oB = (size_t)z * sB;
  const int wave = tid >> 6, lane = tid & 63;
  const int wm = (wave & 1) << 6, wn = (wave >> 1) << 6;
  const int fr = lane & 15, fks = lane >> 4;  // fragment row, global k-slot

  f32x4 acc[4][4];
#pragma unroll
  for (int i = 0; i < 4; i++)
#pragma unroll
    for (int j = 0; j < 4; j++) acc[i][j] = (f32x4)(0.f);

  // Staging: wave w stages rows [w*32, w*32+32) of each array, 2 issues of
  // 16 rows x 64B. Per-lane global address carries the slot swizzle; note
  // ((srow+16)>>1)&3 == (srow>>1)&3 so one swizzle serves both issues.
  const int srow = (wave << 5) + (lane >> 2);
  const int gso = ((lane & 3) ^ ((srow >> 1) & 3)) << 3;  // swizzled k-slot (shorts)
  const unsigned short* gAH = AH + oA + (size_t)(bm + srow) * 1024 + gso;
  const unsigned short* gAL = AL + oA + (size_t)(bm + srow) * 1024 + gso;
  const unsigned short* gBH = BH + oB + (size_t)(bn + srow) * 1024 + gso;
  const unsigned short* gBL = BL + oB + (size_t)(bn + srow) * 1024 + gso;
  unsigned short* lAh = Ahs + (wave << 10);
  unsigned short* lAl = Als + (wave << 10);
  unsigned short* lBh = Bhs + (wave << 10);
  unsigned short* lBl = Bls + (wave << 10);

  // Fragment-read offsets (loop-invariant, swizzled to match staging)
  int roA[4], roB[4];
#pragma unroll
  for (int i = 0; i < 4; i++) {
    int rr = wm + (i << 4) + fr;
    roA[i] = rr * 32 + ((fks ^ ((rr >> 1) & 3)) << 3);
    rr = wn + (i << 4) + fr;
    roB[i] = rr * 32 + ((fks ^ ((rr >> 1) & 3)) << 3);
  }

#pragma unroll 1
  for (int k0 = 0; k0 < 1024; k0 += 32) {
    __syncthreads();  // prior compute done reading LDS
    gload16(gAH + k0, lAh);
    gload16(gAH + k0 + 16384, lAh + 512);
    gload16(gAL + k0, lAl);
    gload16(gAL + k0 + 16384, lAl + 512);
    gload16(gBH + k0, lBh);
    gload16(gBH + k0 + 16384, lBh + 512);
    gload16(gBL + k0, lBl);
    gload16(gBL + k0 + 16384, lBl + 512);
    __syncthreads();  // vmcnt drained before barrier -> LDS tile ready

    s16x8 ah[4], al[4];
#pragma unroll
    for (int i = 0; i < 4; i++) {
      ah[i] = *(const s16x8*)&Ahs[roA[i]];
      al[i] = *(const s16x8*)&Als[roA[i]];
    }
#pragma unroll
    for (int j = 0; j < 4; j++) {
      s16x8 bh = *(const s16x8*)&Bhs[roB[j]];
      s16x8 bl = *(const s16x8*)&Bls[roB[j]];
#pragma unroll
      for (int i = 0; i < 4; i++) {
        acc[i][j] = __builtin_amdgcn_mfma_f32_16x16x32_bf16(al[i], bh, acc[i][j], 0, 0, 0);
        acc[i][j] = __builtin_amdgcn_mfma_f32_16x16x32_bf16(ah[i], bl, acc[i][j], 0, 0, 0);
        acc[i][j] = __builtin_amdgcn_mfma_f32_16x16x32_bf16(ah[i], bh, acc[i][j], 0, 0, 0);
      }
    }
  }
  const int cr = (lane >> 4) << 2;
  if (SPLIT_OUT) {
    unsigned short* CH = (unsigned short*)Cout + (size_t)z * sC;
    unsigned short* CL = (unsigned short*)CoutL + (size_t)z * sC;
#pragma unroll
    for (int i = 0; i < 4; i++)
#pragma unroll
      for (int r = 0; r < 4; r++) {
        size_t base = (size_t)(bm + wm + (i << 4) + cr + r) * 1024 + bn + wn + fr;
#pragma unroll
        for (int j = 0; j < 4; j++) {
          float f = acc[i][j][r];
          unsigned short h = f2bf_rn(f);
          CH[base + (j << 4)] = h;
          CL[base + (j << 4)] = f2bf_rn(f - bf2f(h));
        }
      }
  } else {
    float* C = (float*)Cout + (size_t)z * sC;
#pragma unroll
    for (int i = 0; i < 4; i++)
#pragma unroll
      for (int r = 0; r < 4; r++) {
        float* cp = C + (size_t)(bm + wm + (i << 4) + cr + r) * 1024 + bn + wn + fr;
#pragma unroll
        for (int j = 0; j < 4; j++) cp[j << 4] = acc[i][j][r];
      }
  }
}

// ---------------------------------------------------------------------------
// Plain bf16 GEMM: C = A * B^T fp32 out; same gload-LDS + swizzle structure.
// Grid: flat 1024 blocks (8x8x16), XCD-swizzled.
// ---------------------------------------------------------------------------
__global__ __launch_bounds__(256) void gemm_bf16(
    const unsigned short* __restrict__ A, const unsigned short* __restrict__ B,
    float* __restrict__ C, long long sA, long long sB, long long sC) {
  __shared__ unsigned short Ahs[128 * 32];
  __shared__ unsigned short Bhs[128 * 32];
  const int tid = threadIdx.x;
  const int wg = ((blockIdx.x & 7) << 7) | (blockIdx.x >> 3);
  const int z = wg >> 6;
  const int bm = ((wg >> 3) & 7) << 7, bn = (wg & 7) << 7;
  A += (size_t)z * sA; B += (size_t)z * sB; C += (size_t)z * sC;
  const int wave = tid >> 6, lane = tid & 63;
  const int wm = (wave & 1) << 6, wn = (wave >> 1) << 6;
  const int fr = lane & 15, fks = lane >> 4;

  f32x4 acc[4][4];
#pragma unroll
  for (int i = 0; i < 4; i++)
#pragma unroll
    for (int j = 0; j < 4; j++) acc[i][j] = (f32x4)(0.f);

  const int srow = (wave << 5) + (lane >> 2);
  const int gso = ((lane & 3) ^ ((srow >> 1) & 3)) << 3;
  const unsigned short* gA = A + (size_t)(bm + srow) * 1024 + gso;
  const unsigned short* gB = B + (size_t)(bn + srow) * 1024 + gso;
  unsigned short* lA = Ahs + (wave << 10);
  unsigned short* lB = Bhs + (wave << 10);

  int roA[4], roB[4];
#pragma unroll
  for (int i = 0; i < 4; i++) {
    int rr = wm + (i << 4) + fr;
    roA[i] = rr * 32 + ((fks ^ ((rr >> 1) & 3)) << 3);
    rr = wn + (i << 4) + fr;
    roB[i] = rr * 32 + ((fks ^ ((rr >> 1) & 3)) << 3);
  }

#pragma unroll 1
  for (int k0 = 0; k0 < 1024; k0 += 32) {
    __syncthreads();
    gload16(gA + k0, lA);
    gload16(gA + k0 + 16384, lA + 512);
    gload16(gB + k0, lB);
    gload16(gB + k0 + 16384, lB + 512);
    __syncthreads();

    s16x8 ah[4];
#pragma unroll
    for (int i = 0; i < 4; i++) ah[i] = *(const s16x8*)&Ahs[roA[i]];
#pragma unroll
    for (int j = 0; j < 4; j++) {
      s16x8 bh = *(const s16x8*)&Bhs[roB[j]];
#pragma unroll
      for (int i = 0; i < 4; i++)
        acc[i][j] = __builtin_amdgcn_mfma_f32_16x16x32_bf16(ah[i], bh, acc[i][j], 0, 0, 0);
    }
  }
  const int cr = (lane >> 4) << 2;
#pragma unroll
  for (int i = 0; i < 4; i++)
#pragma unroll
    for (int r = 0; r < 4; r++) {
      float* cp = C + (size_t)(bm + wm + (i << 4) + cr + r) * 1024 + bn + wn + fr;
#pragma unroll
      for (int j = 0; j < 4; j++) cp[j << 4] = acc[i][j][r];
    }
}

// ---------------------------------------------------------------------------
// Wave reductions
// ---------------------------------------------------------------------------
__device__ inline float waveMax(float v) {
#pragma unroll
  for (int o = 32; o > 0; o >>= 1) v = fmaxf(v, __shfl_down(v, o, 64));
  return v;
}
__device__ inline float waveSum(float v) {
#pragma unroll
  for (int o = 32; o > 0; o >>= 1) v += __shfl_down(v, o, 64);
  return v;
}

// ---------------------------------------------------------------------------
// edit_weights = masked row softmax(sim) -> bf16. One block per (b,e) row.
// ---------------------------------------------------------------------------
__global__ __launch_bounds__(256) void row_softmax_kernel(
    const float* __restrict__ sim, const int* __restrict__ smask,
    unsigned short* __restrict__ out) {
  const int row = blockIdx.x;  // b*1024 + e
  const int b = row >> 10;
  const float* x = sim + ((size_t)row << 10);
  const int* mk = smask + (b << 10);
  const int t = threadIdx.x;

  float4 v = ((const float4*)x)[t];
  int4 m = ((const int4*)mk)[t];
  float vv[4] = {v.x, v.y, v.z, v.w};
  const int mmv[4] = {m.x, m.y, m.z, m.w};

  float mx = -3.0e38f;
#pragma unroll
  for (int i = 0; i < 4; i++)
    if (!mmv[i]) mx = fmaxf(mx, vv[i]);

  __shared__ float red[4];
  float wmx = waveMax(mx);
  const int wave = t >> 6;
  if ((t & 63) == 0) red[wave] = wmx;
  __syncthreads();
  mx = fmaxf(fmaxf(red[0], red[1]), fmaxf(red[2], red[3]));
  __syncthreads();

  float s = 0.f;
#pragma unroll
  for (int i = 0; i < 4; i++) {
    float e = mmv[i] ? 0.f : __expf(vv[i] - mx);
    vv[i] = e;
    s += e;
  }
  float ws = waveSum(s);
  if ((t & 63) == 0) red[wave] = ws;
  __syncthreads();
  s = red[0] + red[1] + red[2] + red[3];
  float inv = 1.0f / s;

  ushort4 o;
  o.x = f2bf_rn(vv[0] * inv);
  o.y = f2bf_rn(vv[1] * inv);
  o.z = f2bf_rn(vv[2] * inv);
  o.w = f2bf_rn(vv[3] * inv);
  *(ushort4*)&out[((size_t)row << 10) + (t << 2)] = o;
}

// ---------------------------------------------------------------------------
// Col-softmax phase A: partial (max, sum) over 64-row e-chunks.
// ---------------------------------------------------------------------------
__global__ __launch_bounds__(256) void col_partial(
    const float* __restrict__ sim, const int* __restrict__ emask,
    float* __restrict__ pmax, float* __restrict__ psum) {
  const int b = blockIdx.z;
  const int ec = blockIdx.y;
  const int l = (blockIdx.x << 8) + threadIdx.x;
  const float* p = sim + ((size_t)b << 20) + (((size_t)ec << 6) << 10) + l;
  const int* mk = emask + (b << 10) + (ec << 6);
  float mx0 = -1.0e30f, s0 = 0.f, mx1 = -1.0e30f, s1 = 0.f;
#pragma unroll 4
  for (int i = 0; i < 64; i += 2) {
    float v0 = mk[i] ? -3.0e38f : p[(size_t)i << 10];
    float v1 = mk[i + 1] ? -3.0e38f : p[(size_t)(i + 1) << 10];
    float n0 = fmaxf(mx0, v0);
    s0 = s0 * __expf(mx0 - n0) + __expf(v0 - n0);
    mx0 = n0;
    float n1 = fmaxf(mx1, v1);
    s1 = s1 * __expf(mx1 - n1) + __expf(v1 - n1);
    mx1 = n1;
  }
  float M = fmaxf(mx0, mx1);
  float S = s0 * __expf(mx0 - M) + s1 * __expf(mx1 - M);
  const int o = (((b << 4) + ec) << 10) + l;
  pmax[o] = M;
  psum[o] = S;
}

// ---------------------------------------------------------------------------
// Col-softmax phase C: combine partials; write TRANSPOSED bf16 wT[b][l][e].
// ---------------------------------------------------------------------------
__global__ __launch_bounds__(256) void col_weights_T(
    const float* __restrict__ sim, const int* __restrict__ emask,
    const float* __restrict__ pmax, const float* __restrict__ psum,
    unsigned short* __restrict__ wT) {
  const int b = blockIdx.z;
  const int l0 = blockIdx.x << 6;
  const int e0 = blockIdx.y << 6;
  const int t = threadIdx.x;
  __shared__ float Ml[64], Il[64];
  __shared__ int msk[64];
  __shared__ float gm[4][64], gs[4][64];
  __shared__ unsigned short tile[64][72];

  {
    const int ll = t & 63, g = t >> 6;
    float m = -1.0e30f, s = 0.f;
#pragma unroll
    for (int q = 0; q < 4; q++) {
      int ec = g + (q << 2);
      const int o = (((b << 4) + ec) << 10) + l0 + ll;
      float pm = pmax[o], ps = psum[o];
      float nm = fmaxf(m, pm);
      s = s * __expf(m - nm) + ps * __expf(pm - nm);
      m = nm;
    }
    gm[g][ll] = m;
    gs[g][ll] = s;
    __syncthreads();
    if (t < 64) {
      float M = fmaxf(fmaxf(gm[0][t], gm[1][t]), fmaxf(gm[2][t], gm[3][t]));
      float S = 0.f;
#pragma unroll
      for (int q = 0; q < 4; q++) S += gs[q][t] * __expf(gm[q][t] - M);
      Ml[t] = M;
      Il[t] = 1.0f / S;
      msk[t] = emask[(b << 10) + e0 + t];
    }
    __syncthreads();
  }

  const int lane = t & 63, wv = t >> 6;
#pragma unroll
  for (int i = 0; i < 16; i++) {
    const int el = (wv << 4) + i;
    float v = sim[((size_t)b << 20) + ((size_t)(e0 + el) << 10) + l0 + lane];
    float w = msk[el] ? 0.f : __expf(v - Ml[lane]) * Il[lane];
    tile[lane][el] = f2bf_rn(w);
  }
  __syncthreads();
  const int r = t >> 2, seg = (t & 3) << 4;
  u16x8 v0 = *(const u16x8*)&tile[r][seg];
  u16x8 v1 = *(const u16x8*)&tile[r][seg + 8];
  size_t o = ((size_t)((b << 10) + l0 + r) << 10) + e0 + seg;
  *(u16x8*)&wT[o] = v0;
  *(u16x8*)&wT[o + 8] = v1;
}

// ---------------------------------------------------------------------------
// bf16 64x64 transpose: XT[b][d][l] = X[b][l][d].
// ---------------------------------------------------------------------------
__global__ __launch_bounds__(256) void transpose16(
    const unsigned short* __restrict__ X, unsigned short* __restrict__ XT) {
  __shared__ unsigned short ts[64][72];
  const int b = blockIdx.z;
  const int d0 = blockIdx.x << 6, l0 = blockIdx.y << 6;
  const int t = threadIdx.x;
  const unsigned short* Xb = X + ((size_t)b << 20);
  unsigned short* Tb = XT + ((size_t)b << 20);
  const int row = t >> 2, seg = (t & 3) << 4;
  u16x8 v0 = *(const u16x8*)&Xb[((size_t)(l0 + row) << 10) + d0 + seg];
  u16x8 v1 = *(const u16x8*)&Xb[((size_t)(l0 + row) << 10) + d0 + seg + 8];
#pragma unroll
  for (int i = 0; i < 8; i++) ts[seg + i][row] = v0[i];
#pragma unroll
  for (int i = 0; i < 8; i++) ts[seg + 8 + i][row] = v1[i];
  __syncthreads();
  u16x8 o0 = *(const u16x8*)&ts[row][seg];
  u16x8 o1 = *(const u16x8*)&ts[row][seg + 8];
  size_t o = ((size_t)(d0 + row) << 10) + l0 + seg;
  *(u16x8*)&Tb[o] = o0;
  *(u16x8*)&Tb[o + 8] = o1;
}

// ---------------------------------------------------------------------------
// Buffer plan (ws = 128 MB, d_out = 128 MB used as scratch until outputs):
//  ws[0,32):    editH                 (live until src_ctx transposes)
//  ws[32,64):   srcH  -> editT        (after srcT transpose consumes srcH)
//  ws[64,96):   projH -> wE
//  ws[96,128):  projL -> wST
//  dout[0,32):  editL -> sim(lo half) -> out_edit
//  dout[32,64):          sim(hi half) -> out_edit
//  dout[64,96): srcL  -> pmax/psum(2MB) -> srcT -> out_src
//  dout[96,100): WH,WL                 -> out_src
// ---------------------------------------------------------------------------
extern "C" void kernel_launch(void* const* d_in, const int* in_sizes, int n_in,
                              void* d_out, int out_size, void* d_ws,
                              size_t ws_size, hipStream_t stream) {
  const float* edit = (const float*)d_in[0];
  const float* src = (const float*)d_in[1];
  const int* emask = (const int*)d_in[2];
  const int* smask = (const int*)d_in[3];
  const float* W = (const float*)d_in[4];

  char* ws = (char*)d_ws;
  char* dob = (char*)d_out;

  unsigned short* eH = (unsigned short*)ws;
  unsigned short* sH = (unsigned short*)(ws + ((size_t)32 << 20));
  unsigned short* pH = (unsigned short*)(ws + ((size_t)64 << 20));
  unsigned short* pL = (unsigned short*)(ws + ((size_t)96 << 20));
  unsigned short* wE = pH;   // after proj GEMM consumed
  unsigned short* wST = pL;
  unsigned short* editT = sH;  // after srcH consumed by its transpose

  unsigned short* eL = (unsigned short*)dob;
  unsigned short* sL = (unsigned short*)(dob + ((size_t)64 << 20));
  unsigned short* WH = (unsigned short*)(dob + ((size_t)96 << 20));
  unsigned short* WL = (unsigned short*)(dob + ((size_t)98 << 20));
  float* sim = (float*)dob;                                  // [0,64)
  float* pmax = (float*)(dob + ((size_t)64 << 20));
  float* psum = (float*)(dob + ((size_t)65 << 20));
  unsigned short* srcT = (unsigned short*)(dob + ((size_t)64 << 20));
  float* out_edit = (float*)dob;
  float* out_src = (float*)(dob + ((size_t)64 << 20));

  const long long S1 = 1LL << 20;
  dim3 blk(256);

  // P1: split conversions
  cvt_split<<<dim3(16384), blk, 0, stream>>>(edit, eH, eL);
  cvt_split<<<dim3(16384), blk, 0, stream>>>(src, sH, sL);
  cvt_split<<<dim3(1024), blk, 0, stream>>>(W, WH, WL);

  // P2: proj = edit @ W^T -> hi/lo bf16 (M=16384 flattened, N=1024)
  gemm_split3b<1><<<dim3(1024), blk, 0, stream>>>(
      eH, eL, WH, WL, (void*)pH, (void*)pL, 0, 0, 0);

  // P3: sim[b] = proj[b] @ src[b]^T -> fp32 (in d_out[0,64MB))
  gemm_split3b<0><<<dim3(1024), blk, 0, stream>>>(
      pH, pL, sH, sL, (void*)sim, nullptr, S1, S1, S1);

  // P4: softmaxes
  row_softmax_kernel<<<dim3(BATCH << 10), blk, 0, stream>>>(sim, smask, wE);
  col_partial<<<dim3(4, 16, BATCH), blk, 0, stream>>>(sim, emask, pmax, psum);
  col_weights_T<<<dim3(16, 16, BATCH), blk, 0, stream>>>(sim, emask, pmax, psum, wST);

  // P5: transposes (bf16): srcT = srcH^T, editT = editH^T (overwrites srcH)
  transpose16<<<dim3(16, 16, BATCH), blk, 0, stream>>>(sH, srcT);
  transpose16<<<dim3(16, 16, BATCH), blk, 0, stream>>>(eH, editT);

  // P6: ctx GEMMs. edit_ctx FIRST (reads srcT in dout[64,96) before src_ctx
  // overwrites it; writes dout[0,64) over dead sim).
  gemm_bf16<<<dim3(1024), blk, 0, stream>>>(wE, srcT, out_edit, S1, S1, S1);
  gemm_bf16<<<dim3(1024), blk, 0, stream>>>(wST, editT, out_src, S1, S1, S1);
}

// Round 3
// 549.658 us; speedup vs baseline: 1.2128x; 1.1314x over previous
//
#include <hip/hip_runtime.h>
#include <math.h>

#define BATCH 16

typedef __attribute__((ext_vector_type(8))) short s16x8;
typedef __attribute__((ext_vector_type(8))) unsigned short u16x8;
typedef __attribute__((ext_vector_type(4))) float f32x4;

__device__ inline unsigned short f2bf_rn(float f) {
  unsigned u = __float_as_uint(f);
  u += 0x7FFF + ((u >> 16) & 1);
  return (unsigned short)(u >> 16);
}
__device__ inline float bf2f(unsigned short h) {
  return __uint_as_float(((unsigned)h) << 16);
}

// Async global->LDS DMA, 16B per lane. LDS dest is wave-uniform base + lane*16.
__device__ __forceinline__ void gload16(const unsigned short* g, unsigned short* l) {
  __builtin_amdgcn_global_load_lds(
      (__attribute__((address_space(1))) void*)g,
      (__attribute__((address_space(3))) void*)l, 16, 0, 0);
}

// ---------------------------------------------------------------------------
// Elementwise fp32 -> (bf16 hi, bf16 lo) split. 4 elems/thread.
// ---------------------------------------------------------------------------
__global__ __launch_bounds__(256) void cvt_split(
    const float* __restrict__ X, unsigned short* __restrict__ H,
    unsigned short* __restrict__ L) {
  const size_t i = (((size_t)blockIdx.x << 8) + threadIdx.x) << 2;
  f32x4 v = *(const f32x4*)(X + i);
  ushort4 h, l;
  h.x = f2bf_rn(v[0]); l.x = f2bf_rn(v[0] - bf2f(h.x));
  h.y = f2bf_rn(v[1]); l.y = f2bf_rn(v[1] - bf2f(h.y));
  h.z = f2bf_rn(v[2]); l.z = f2bf_rn(v[2] - bf2f(h.z));
  h.w = f2bf_rn(v[3]); l.w = f2bf_rn(v[3] - bf2f(h.w));
  *(ushort4*)(H + i) = h;
  *(ushort4*)(L + i) = l;
}

__global__ __launch_bounds__(256) void cvt_split2(
    const float* __restrict__ X0, unsigned short* __restrict__ H0,
    unsigned short* __restrict__ L0, const float* __restrict__ X1,
    unsigned short* __restrict__ H1, unsigned short* __restrict__ L1) {
  const int bid = blockIdx.x;
  const float* X;
  unsigned short *H, *L;
  size_t base;
  if (bid < 16384) { X = X0; H = H0; L = L0; base = (size_t)bid << 8; }
  else { X = X1; H = H1; L = L1; base = (size_t)(bid - 16384) << 8; }
  const size_t i = (base + threadIdx.x) << 2;
  f32x4 v = *(const f32x4*)(X + i);
  ushort4 h, l;
  h.x = f2bf_rn(v[0]); l.x = f2bf_rn(v[0] - bf2f(h.x));
  h.y = f2bf_rn(v[1]); l.y = f2bf_rn(v[1] - bf2f(h.y));
  h.z = f2bf_rn(v[2]); l.z = f2bf_rn(v[2] - bf2f(h.z));
  h.w = f2bf_rn(v[3]); l.w = f2bf_rn(v[3] - bf2f(h.w));
  *(ushort4*)(H + i) = h;
  *(ushort4*)(L + i) = l;
}

// ---------------------------------------------------------------------------
// 256x256-tile phase-split GEMM (T3+T4+T5 schedule), C = A*B^T.
// HILO=1: split-bf16 3-MFMA fp32-accurate product (A=(AH,AL), B=(BH,BL)).
// SPLIT_OUT=1: write C as (CH,CL) bf16 hi/lo; else fp32 C.
// BK=32, 8 waves (2M x 4N), per-wave 128x64 output, LDS 128KiB (HILO) / 64KiB.
// Staging via global_load_lds with slot-XOR swizzle (slot ^= (row>>1)&3)
// applied on global source AND frag read (verified conflict-free, r1: 0 cnf).
// Loop: 4 quadrant phases x {ds_read; prefetch-issue; s_barrier; setprio(1);
// MFMA cluster; setprio(0); s_barrier}; ONE __syncthreads() (vmcnt drain) per
// K-tile — only iteration-old prefetch loads outstanding there. Raw phase
// barriers do NOT drain vmcnt: DMA stays in flight across them.
// Grid: flat 256 blocks (1/CU), bijective XCD swizzle.
// ---------------------------------------------------------------------------
template <int HILO, int SPLIT_OUT>
__global__ __launch_bounds__(512, 2) void gemm8p(
    const unsigned short* __restrict__ AH, const unsigned short* __restrict__ AL,
    const unsigned short* __restrict__ BH, const unsigned short* __restrict__ BL,
    void* __restrict__ Cout, void* __restrict__ CoutL,
    long long sA, long long sB, long long sC, int batched) {
  constexpr int NARR = HILO ? 4 : 2;  // 0=AH,1=BH,2=AL,3=BL
  __shared__ __align__(16) unsigned short lds[2][NARR][8192];  // [dbuf][arr][256*32]
  const int tid = threadIdx.x;
  // XCD swizzle: 256 blocks -> 32 consecutive tiles per XCD
  const int wg = ((blockIdx.x & 7) << 5) | (blockIdx.x >> 3);
  int z, bm, bn;
  if (batched) {  // 16 batches x 4x4 tiles of 1024^2
    z = wg >> 4; bm = ((wg >> 2) & 3) << 8; bn = (wg & 3) << 8;
  } else {        // M=16384 flat x N=1024: 64x4 tiles
    z = 0; bm = (wg >> 2) << 8; bn = (wg & 3) << 8;
  }
  const int wave = tid >> 6, lane = tid & 63;
  const int wm = wave >> 2, wn = wave & 3;      // 2 x 4 wave grid
  const int fr = lane & 15, fks = lane >> 4;    // frag row, k-slot

  // Staging addresses: 512 threads cover 128 rows x 64B per issue (q=0/1).
  const int svrow = tid >> 2;                                  // 0..127
  const int scol = ((tid & 3) ^ ((tid >> 3) & 3)) << 3;        // swizzled k-slot
  const unsigned short* gA0 = AH + (size_t)z * sA + (size_t)(bm + svrow) * 1024 + scol;
  const unsigned short* gB0 = BH + (size_t)z * sB + (size_t)(bn + svrow) * 1024 + scol;
  const unsigned short* gA1 = HILO ? (AL + (size_t)z * sA + (size_t)(bm + svrow) * 1024 + scol) : gA0;
  const unsigned short* gB1 = HILO ? (BL + (size_t)z * sB + (size_t)(bn + svrow) * 1024 + scol) : gB0;
  const int lwb = wave << 9;  // wave's 16-row LDS chunk base (shorts), q adds 4096

  // Fragment-read offsets (loop-invariant, swizzle matches staging)
  int aoff[8], boff[4];
#pragma unroll
  for (int m = 0; m < 8; m++) {
    const int r = (wm << 7) + (m << 4) + fr;
    aoff[m] = (r << 5) + ((fks ^ ((r >> 1) & 3)) << 3);
  }
#pragma unroll
  for (int n = 0; n < 4; n++) {
    const int r = (wn << 6) + (n << 4) + fr;
    boff[n] = (r << 5) + ((fks ^ ((r >> 1) & 3)) << 3);
  }

  f32x4 acc[8][4];
#pragma unroll
  for (int m = 0; m < 8; m++)
#pragma unroll
    for (int n = 0; n < 4; n++) acc[m][n] = (f32x4)(0.f);

#define ISS(NXT, ARR, G, Q, KO) \
  gload16((G) + ((size_t)(Q) << 17) + (KO), &lds[NXT][ARR][((Q) << 12) + lwb])

  // Prologue: stage tile 0 into buf 0, drain, barrier.
  ISS(0, 0, gA0, 0, 0); ISS(0, 0, gA0, 1, 0);
  ISS(0, 1, gB0, 0, 0); ISS(0, 1, gB0, 1, 0);
  if (HILO) {
    ISS(0, 2, gA1, 0, 0); ISS(0, 2, gA1, 1, 0);
    ISS(0, 3, gB1, 0, 0); ISS(0, 3, gB1, 1, 0);
  }
  __syncthreads();

#pragma unroll 1
  for (int kt = 0; kt < 32; ++kt) {
    const int cur = kt & 1, nxt = cur ^ 1;
    const int kn = (kt + 1) << 5;  // next tile k-offset (shorts)
    const bool pf = kt < 31;
    const unsigned short* LAH = lds[cur][0];
    const unsigned short* LBH = lds[cur][1];
    const unsigned short* LAL = lds[cur][HILO ? 2 : 0];
    const unsigned short* LBL = lds[cur][HILO ? 3 : 1];
    s16x8 ah[4], al[4], bh[2], bl[2];

#define LDA8(QM)                                                         \
  do {                                                                   \
    _Pragma("unroll") for (int m_ = 0; m_ < 4; m_++) {                   \
      const int o_ = aoff[((QM) << 2) + m_];                             \
      ah[m_] = *(const s16x8*)&LAH[o_];                                  \
      if (HILO) al[m_] = *(const s16x8*)&LAL[o_];                        \
    }                                                                    \
  } while (0)
#define LDB4(QN)                                                         \
  do {                                                                   \
    _Pragma("unroll") for (int n_ = 0; n_ < 2; n_++) {                   \
      const int o_ = boff[((QN) << 1) + n_];                             \
      bh[n_] = *(const s16x8*)&LBH[o_];                                  \
      if (HILO) bl[n_] = *(const s16x8*)&LBL[o_];                        \
    }                                                                    \
  } while (0)
#define MM8(QM, QN)                                                              \
  do {                                                                           \
    _Pragma("unroll") for (int m_ = 0; m_ < 4; m_++)                             \
        _Pragma("unroll") for (int n_ = 0; n_ < 2; n_++) {                       \
      const int M_ = ((QM) << 2) + m_, N_ = ((QN) << 1) + n_;                    \
      if (HILO) {                                                                \
        acc[M_][N_] = __builtin_amdgcn_mfma_f32_16x16x32_bf16(al[m_], bh[n_],    \
                                                              acc[M_][N_], 0, 0, 0); \
        acc[M_][N_] = __builtin_amdgcn_mfma_f32_16x16x32_bf16(ah[m_], bl[n_],    \
                                                              acc[M_][N_], 0, 0, 0); \
      }                                                                          \
      acc[M_][N_] = __builtin_amdgcn_mfma_f32_16x16x32_bf16(ah[m_], bh[n_],      \
                                                            acc[M_][N_], 0, 0, 0);   \
    }                                                                            \
  } while (0)

    // ---- phase (qm=0, qn=0): A frags m0-3, B frags n0-1; prefetch A of kt+1
    LDA8(0); LDB4(0);
    if (pf) {
      ISS(nxt, 0, gA0, 0, kn); ISS(nxt, 0, gA0, 1, kn);
      if (HILO) { ISS(nxt, 2, gA1, 0, kn); ISS(nxt, 2, gA1, 1, kn); }
    }
    __builtin_amdgcn_s_barrier();
    __builtin_amdgcn_s_setprio(1); MM8(0, 0); __builtin_amdgcn_s_setprio(0);
    __builtin_amdgcn_s_barrier();

    // ---- phase (0,1): B frags n2-3; prefetch B of kt+1
    LDB4(1);
    if (pf) {
      ISS(nxt, 1, gB0, 0, kn); ISS(nxt, 1, gB0, 1, kn);
      if (HILO) { ISS(nxt, 3, gB1, 0, kn); ISS(nxt, 3, gB1, 1, kn); }
    }
    __builtin_amdgcn_s_barrier();
    __builtin_amdgcn_s_setprio(1); MM8(0, 1); __builtin_amdgcn_s_setprio(0);
    __builtin_amdgcn_s_barrier();

    // ---- phase (1,0)
    LDA8(1); LDB4(0);
    __builtin_amdgcn_s_barrier();
    __builtin_amdgcn_s_setprio(1); MM8(1, 0); __builtin_amdgcn_s_setprio(0);
    __builtin_amdgcn_s_barrier();

    // ---- phase (1,1)
    LDB4(1);
    __builtin_amdgcn_s_barrier();
    __builtin_amdgcn_s_setprio(1); MM8(1, 1); __builtin_amdgcn_s_setprio(0);
    // Iteration end: only this iteration's prefetch (issued >=2 phases ago)
    // is outstanding -> cheap drain; frees buf[cur] for next prefetch.
    __syncthreads();
#undef LDA8
#undef LDB4
#undef MM8
  }
#undef ISS

  const int cr = (lane >> 4) << 2;
  const int crow0 = bm + (wm << 7);
  const int ccol0 = bn + (wn << 6);
  if (SPLIT_OUT) {
    unsigned short* CH = (unsigned short*)Cout + (size_t)z * sC;
    unsigned short* CL = (unsigned short*)CoutL + (size_t)z * sC;
#pragma unroll
    for (int m = 0; m < 8; m++)
#pragma unroll
      for (int r = 0; r < 4; r++) {
        const size_t base = (size_t)(crow0 + (m << 4) + cr + r) * 1024 + ccol0 + fr;
#pragma unroll
        for (int n = 0; n < 4; n++) {
          float f = acc[m][n][r];
          unsigned short h = f2bf_rn(f);
          CH[base + (n << 4)] = h;
          CL[base + (n << 4)] = f2bf_rn(f - bf2f(h));
        }
      }
  } else {
    float* C = (float*)Cout + (size_t)z * sC;
#pragma unroll
    for (int m = 0; m < 8; m++)
#pragma unroll
      for (int r = 0; r < 4; r++) {
        float* cp = C + (size_t)(crow0 + (m << 4) + cr + r) * 1024 + ccol0 + fr;
#pragma unroll
        for (int n = 0; n < 4; n++) cp[n << 4] = acc[m][n][r];
      }
  }
}

// ---------------------------------------------------------------------------
// Wave reductions
// ---------------------------------------------------------------------------
__device__ inline float waveMax(float v) {
#pragma unroll
  for (int o = 32; o > 0; o >>= 1) v = fmaxf(v, __shfl_down(v, o, 64));
  return v;
}
__device__ inline float waveSum(float v) {
#pragma unroll
  for (int o = 32; o > 0; o >>= 1) v += __shfl_down(v, o, 64);
  return v;
}

// ---------------------------------------------------------------------------
// edit_weights = masked row softmax(sim) -> bf16. One block per (b,e) row.
// ---------------------------------------------------------------------------
__global__ __launch_bounds__(256) void row_softmax_kernel(
    const float* __restrict__ sim, const int* __restrict__ smask,
    unsigned short* __restrict__ out) {
  const int row = blockIdx.x;  // b*1024 + e
  const int b = row >> 10;
  const float* x = sim + ((size_t)row << 10);
  const int* mk = smask + (b << 10);
  const int t = threadIdx.x;

  float4 v = ((const float4*)x)[t];
  int4 m = ((const int4*)mk)[t];
  float vv[4] = {v.x, v.y, v.z, v.w};
  const int mmv[4] = {m.x, m.y, m.z, m.w};

  float mx = -3.0e38f;
#pragma unroll
  for (int i = 0; i < 4; i++)
    if (!mmv[i]) mx = fmaxf(mx, vv[i]);

  __shared__ float red[4];
  float wmx = waveMax(mx);
  const int wave = t >> 6;
  if ((t & 63) == 0) red[wave] = wmx;
  __syncthreads();
  mx = fmaxf(fmaxf(red[0], red[1]), fmaxf(red[2], red[3]));
  __syncthreads();

  float s = 0.f;
#pragma unroll
  for (int i = 0; i < 4; i++) {
    float e = mmv[i] ? 0.f : __expf(vv[i] - mx);
    vv[i] = e;
    s += e;
  }
  float ws = waveSum(s);
  if ((t & 63) == 0) red[wave] = ws;
  __syncthreads();
  s = red[0] + red[1] + red[2] + red[3];
  float inv = 1.0f / s;

  ushort4 o;
  o.x = f2bf_rn(vv[0] * inv);
  o.y = f2bf_rn(vv[1] * inv);
  o.z = f2bf_rn(vv[2] * inv);
  o.w = f2bf_rn(vv[3] * inv);
  *(ushort4*)&out[((size_t)row << 10) + (t << 2)] = o;
}

// ---------------------------------------------------------------------------
// Col-softmax phase A: partial (max, sum) over 64-row e-chunks.
// ---------------------------------------------------------------------------
__global__ __launch_bounds__(256) void col_partial(
    const float* __restrict__ sim, const int* __restrict__ emask,
    float* __restrict__ pmax, float* __restrict__ psum) {
  const int b = blockIdx.z;
  const int ec = blockIdx.y;
  const int l = (blockIdx.x << 8) + threadIdx.x;
  const float* p = sim + ((size_t)b << 20) + (((size_t)ec << 6) << 10) + l;
  const int* mk = emask + (b << 10) + (ec << 6);
  float mx0 = -1.0e30f, s0 = 0.f, mx1 = -1.0e30f, s1 = 0.f;
#pragma unroll 4
  for (int i = 0; i < 64; i += 2) {
    float v0 = mk[i] ? -3.0e38f : p[(size_t)i << 10];
    float v1 = mk[i + 1] ? -3.0e38f : p[(size_t)(i + 1) << 10];
    float n0 = fmaxf(mx0, v0);
    s0 = s0 * __expf(mx0 - n0) + __expf(v0 - n0);
    mx0 = n0;
    float n1 = fmaxf(mx1, v1);
    s1 = s1 * __expf(mx1 - n1) + __expf(v1 - n1);
    mx1 = n1;
  }
  float M = fmaxf(mx0, mx1);
  float S = s0 * __expf(mx0 - M) + s1 * __expf(mx1 - M);
  const int o = (((b << 4) + ec) << 10) + l;
  pmax[o] = M;
  psum[o] = S;
}

// ---------------------------------------------------------------------------
// Col-softmax phase C: combine partials; write TRANSPOSED bf16 wT[b][l][e].
// ---------------------------------------------------------------------------
__global__ __launch_bounds__(256) void col_weights_T(
    const float* __restrict__ sim, const int* __restrict__ emask,
    const float* __restrict__ pmax, const float* __restrict__ psum,
    unsigned short* __restrict__ wT) {
  const int b = blockIdx.z;
  const int l0 = blockIdx.x << 6;
  const int e0 = blockIdx.y << 6;
  const int t = threadIdx.x;
  __shared__ float Ml[64], Il[64];
  __shared__ int msk[64];
  __shared__ float gm[4][64], gs[4][64];
  __shared__ unsigned short tile[64][72];

  {
    const int ll = t & 63, g = t >> 6;
    float m = -1.0e30f, s = 0.f;
#pragma unroll
    for (int q = 0; q < 4; q++) {
      int ec = g + (q << 2);
      const int o = (((b << 4) + ec) << 10) + l0 + ll;
      float pm = pmax[o], ps = psum[o];
      float nm = fmaxf(m, pm);
      s = s * __expf(m - nm) + ps * __expf(pm - nm);
      m = nm;
    }
    gm[g][ll] = m;
    gs[g][ll] = s;
    __syncthreads();
    if (t < 64) {
      float M = fmaxf(fmaxf(gm[0][t], gm[1][t]), fmaxf(gm[2][t], gm[3][t]));
      float S = 0.f;
#pragma unroll
      for (int q = 0; q < 4; q++) S += gs[q][t] * __expf(gm[q][t] - M);
      Ml[t] = M;
      Il[t] = 1.0f / S;
      msk[t] = emask[(b << 10) + e0 + t];
    }
    __syncthreads();
  }

  const int lane = t & 63, wv = t >> 6;
#pragma unroll
  for (int i = 0; i < 16; i++) {
    const int el = (wv << 4) + i;
    float v = sim[((size_t)b << 20) + ((size_t)(e0 + el) << 10) + l0 + lane];
    float w = msk[el] ? 0.f : __expf(v - Ml[lane]) * Il[lane];
    tile[lane][el] = f2bf_rn(w);
  }
  __syncthreads();
  const int r = t >> 2, seg = (t & 3) << 4;
  u16x8 v0 = *(const u16x8*)&tile[r][seg];
  u16x8 v1 = *(const u16x8*)&tile[r][seg + 8];
  size_t o = ((size_t)((b << 10) + l0 + r) << 10) + e0 + seg;
  *(u16x8*)&wT[o] = v0;
  *(u16x8*)&wT[o + 8] = v1;
}

// ---------------------------------------------------------------------------
// bf16 64x64 transpose, dual-source: z<16 -> (X0->T0, b=z), else (X1->T1).
// ---------------------------------------------------------------------------
__global__ __launch_bounds__(256) void transpose16d(
    const unsigned short* __restrict__ X0, unsigned short* __restrict__ T0,
    const unsigned short* __restrict__ X1, unsigned short* __restrict__ T1) {
  __shared__ unsigned short ts[64][72];
  const int zz = blockIdx.z;
  const int b = zz & 15;
  const unsigned short* Xb = (zz < 16 ? X0 : X1) + ((size_t)b << 20);
  unsigned short* Tb = (zz < 16 ? T0 : T1) + ((size_t)b << 20);
  const int d0 = blockIdx.x << 6, l0 = blockIdx.y << 6;
  const int t = threadIdx.x;
  const int row = t >> 2, seg = (t & 3) << 4;
  u16x8 v0 = *(const u16x8*)&Xb[((size_t)(l0 + row) << 10) + d0 + seg];
  u16x8 v1 = *(const u16x8*)&Xb[((size_t)(l0 + row) << 10) + d0 + seg + 8];
#pragma unroll
  for (int i = 0; i < 8; i++) ts[seg + i][row] = v0[i];
#pragma unroll
  for (int i = 0; i < 8; i++) ts[seg + 8 + i][row] = v1[i];
  __syncthreads();
  u16x8 o0 = *(const u16x8*)&ts[row][seg];
  u16x8 o1 = *(const u16x8*)&ts[row][seg + 8];
  size_t o = ((size_t)(d0 + row) << 10) + l0 + seg;
  *(u16x8*)&Tb[o] = o0;
  *(u16x8*)&Tb[o + 8] = o1;
}

// ---------------------------------------------------------------------------
// Buffer plan (ws = 128 MB, d_out = 128 MB used as scratch until outputs):
//  ws[0,32):    editH                 (live until src_ctx transposes)
//  ws[32,64):   srcH  -> editT        (after srcT transpose consumes srcH)
//  ws[64,96):   projH -> wE
//  ws[96,128):  projL -> wST
//  dout[0,32):  editL -> sim(lo half) -> out_edit
//  dout[32,64):          sim(hi half) -> out_edit
//  dout[64,96): srcL  -> pmax/psum(2MB) -> srcT -> out_src
//  dout[96,100): WH,WL                 -> out_src
// ---------------------------------------------------------------------------
extern "C" void kernel_launch(void* const* d_in, const int* in_sizes, int n_in,
                              void* d_out, int out_size, void* d_ws,
                              size_t ws_size, hipStream_t stream) {
  const float* edit = (const float*)d_in[0];
  const float* src = (const float*)d_in[1];
  const int* emask = (const int*)d_in[2];
  const int* smask = (const int*)d_in[3];
  const float* W = (const float*)d_in[4];

  char* ws = (char*)d_ws;
  char* dob = (char*)d_out;

  unsigned short* eH = (unsigned short*)ws;
  unsigned short* sH = (unsigned short*)(ws + ((size_t)32 << 20));
  unsigned short* pH = (unsigned short*)(ws + ((size_t)64 << 20));
  unsigned short* pL = (unsigned short*)(ws + ((size_t)96 << 20));
  unsigned short* wE = pH;     // after proj GEMM consumed
  unsigned short* wST = pL;
  unsigned short* editT = sH;  // after srcH consumed by its transpose

  unsigned short* eL = (unsigned short*)dob;
  unsigned short* sL = (unsigned short*)(dob + ((size_t)64 << 20));
  unsigned short* WH = (unsigned short*)(dob + ((size_t)96 << 20));
  unsigned short* WL = (unsigned short*)(dob + ((size_t)98 << 20));
  float* sim = (float*)dob;  // [0,64)
  float* pmax = (float*)(dob + ((size_t)64 << 20));
  float* psum = (float*)(dob + ((size_t)65 << 20));
  unsigned short* srcT = (unsigned short*)(dob + ((size_t)64 << 20));
  float* out_edit = (float*)dob;
  float* out_src = (float*)(dob + ((size_t)64 << 20));

  const long long S1 = 1LL << 20;
  dim3 blk(256), blk512(512);

  // P1: split conversions (edit+src merged, W separate)
  cvt_split2<<<dim3(32768), blk, 0, stream>>>(edit, eH, eL, src, sH, sL);
  cvt_split<<<dim3(1024), blk, 0, stream>>>(W, WH, WL);

  // P2: proj = edit @ W^T -> hi/lo bf16 (M=16384 flattened, N=1024)
  gemm8p<1, 1><<<dim3(256), blk512, 0, stream>>>(
      eH, eL, WH, WL, (void*)pH, (void*)pL, 0, 0, 0, 0);

  // P3: sim[b] = proj[b] @ src[b]^T -> fp32 (in d_out[0,64MB))
  gemm8p<1, 0><<<dim3(256), blk512, 0, stream>>>(
      pH, pL, sH, sL, (void*)sim, nullptr, S1, S1, S1, 1);

  // P4: softmaxes
  row_softmax_kernel<<<dim3(BATCH << 10), blk, 0, stream>>>(sim, smask, wE);
  col_partial<<<dim3(4, 16, BATCH), blk, 0, stream>>>(sim, emask, pmax, psum);
  col_weights_T<<<dim3(16, 16, BATCH), blk, 0, stream>>>(sim, emask, pmax, psum, wST);

  // P5: transposes (bf16): srcT = srcH^T, editT = editH^T (overwrites srcH)
  transpose16d<<<dim3(16, 16, 32), blk, 0, stream>>>(sH, srcT, eH, editT);

  // P6: ctx GEMMs. edit_ctx FIRST (reads srcT in dout[64,96) before src_ctx
  // overwrites it; writes dout[0,64) over dead sim).
  gemm8p<0, 0><<<dim3(256), blk512, 0, stream>>>(
      wE, nullptr, srcT, nullptr, (void*)out_edit, nullptr, S1, S1, S1, 1);
  gemm8p<0, 0><<<dim3(256), blk512, 0, stream>>>(
      wST, nullptr, editT, nullptr, (void*)out_src, nullptr, S1, S1, S1, 1);
}